// Round 24
// baseline (169.229 us; speedup 1.0000x reference)
//
#include <hip/hip_runtime.h>
#include <hip/hip_bf16.h>
#include <math.h>

#define B_    2
#define S_    2048
#define HID_  2048
#define NH_   32
#define NKV_  4
#define HD_   64
#define NEGV  (-1e30f)
#define QSCALE 0.1803368802f   /* 0.125 * log2(e) */
#define THR_  11.5f            /* defer-max threshold, log2 units (~e^8) */

typedef __attribute__((ext_vector_type(8))) short bfrag;
typedef __attribute__((ext_vector_type(4))) float f32x4;
typedef __attribute__((ext_vector_type(4))) unsigned u32x4;

__device__ __forceinline__ float ex2(float x) {
    return __builtin_amdgcn_exp2f(x);      // raw v_exp_f32 (2^x)
}

__device__ __forceinline__ float fmax3(float a, float b, float c) {
    return fmaxf(fmaxf(a, b), c);          // clang fuses to v_max3_f32
}

__device__ __forceinline__ short f2bf(float f) {
    unsigned u = __builtin_bit_cast(unsigned, f);
    u += 0x7FFFu + ((u >> 16) & 1u);
    return (short)(u >> 16);
}

__device__ __forceinline__ unsigned cvtpk(float lo, float hi) {
    unsigned w;
    asm("v_cvt_pk_bf16_f32 %0, %1, %2" : "=v"(w) : "v"(lo), "v"(hi));
    return w;
}

__device__ __forceinline__ void glds16(const short* g, short* l) {
    __builtin_amdgcn_global_load_lds(
        (const __attribute__((address_space(1))) void*)(const void*)g,
        (__attribute__((address_space(3))) void*)(void*)l, 16, 0, 0);
}

// cos/sin table: tab[s*64+i]=cos, tab[s*64+32+i]=sin
__global__ void rope_table_k(float* __restrict__ tab) {
    int idx = blockIdx.x * blockDim.x + threadIdx.x;
    if (idx >= S_ * 32) return;
    int s = idx >> 5, i = idx & 31;
    float inv = 1.0f / powf(10000.0f, (float)(2 * i) / 64.0f);
    float ang = (float)s * inv;
    tab[s * 64 + i]      = cosf(ang);
    tab[s * 64 + 32 + i] = sinf(ang);
}

__global__ void f2b_k(const float* __restrict__ in, short* __restrict__ out) {
    int i = (blockIdx.x * blockDim.x + threadIdx.x) * 4;
    float4 v = *(const float4*)(in + i);
    short4 o;
    o.x = f2bf(v.x); o.y = f2bf(v.y); o.z = f2bf(v.z); o.w = f2bf(v.w);
    *(short4*)(out + i) = o;
}

// fp32 (R x C) -> bf16 transposed (C x R)
__global__ void transpose_f2b(const float* __restrict__ in, short* __restrict__ out,
                              int R, int C) {
    __shared__ float t[32][33];
    int c0 = blockIdx.x * 32, r0 = blockIdx.y * 32;
    int x = threadIdx.x, y = threadIdx.y;  // 32 x 8
    #pragma unroll
    for (int i = 0; i < 32; i += 8) t[y + i][x] = in[(size_t)(r0 + y + i) * C + c0 + x];
    __syncthreads();
    #pragma unroll
    for (int i = 0; i < 32; i += 8)
        out[(size_t)(c0 + y + i) * R + r0 + x] = f2bf(t[x][y + i]);
}

// bf16 MFMA GEMM: C[M,N] = A[M,K] @ Bt[N,K]^T. BM x BN tile, BK in {32,64}.
// LDS stored as [2][BK/32][rows][32] so every 32-k chunk keeps the lane-linear
// global_load_lds layout. SWZ: bijective XCD-aware block swizzle (nwg%8==0).
template<int BM, int BN, int BK, bool OUT_BF16, bool SWZ>
__global__ __launch_bounds__(256)
void mgemm(const short* __restrict__ A, const short* __restrict__ Bt,
           void* __restrict__ Cout, int M, int N, int K) {
    constexpr int KC = BK / 32;
    __shared__ short As[2][KC][BM][32];
    __shared__ short Bs[2][KC][BN][32];
    const int tid = threadIdx.x;
    const int wv = tid >> 6, lane = tid & 63;
    const int g = lane >> 4, r = lane & 15;
    constexpr int MI = (BM == 128 && BN == 128) ? 4 : (BM == 128 ? 2 : 1);
    constexpr int NI = 4;
    const int rowb = (BM == 128 && BN == 128) ? (wv >> 1) * 64
                   : (BM == 128 ? wv * 32 : wv * 16);
    const int colb = (BM == 128 && BN == 128) ? (wv & 1) * 64 : 0;

    int bx = blockIdx.x, by = blockIdx.y;
    if (SWZ) {
        int nwg = gridDim.x * gridDim.y;
        int bid = by * gridDim.x + bx;
        int cpx = nwg >> 3;
        int sid = (bid & 7) * cpx + (bid >> 3);
        bx = sid % gridDim.x;
        by = sid / gridDim.x;
    }
    const int row0 = by * BM;
    const int col0 = bx * BN;

    f32x4 acc[MI][NI];
    #pragma unroll
    for (int i = 0; i < MI; ++i)
        #pragma unroll
        for (int j = 0; j < NI; ++j) { f32x4 z = {0.f,0.f,0.f,0.f}; acc[i][j] = z; }

    const int srow = tid >> 2;          // 0..63
    const int schk = (tid & 3) * 8;     // 0,8,16,24
    const short* Asrc = A + (size_t)(row0 + srow) * K + schk;
    const short* Bsrc = Bt + (size_t)(col0 + srow) * K + schk;

    const int nk = K / BK;

    auto stage = [&](int buf, int k0) {
        #pragma unroll
        for (int c = 0; c < KC; ++c) {
            glds16(Asrc + k0 + c * 32, &As[buf][c][srow][schk]);
            if (BM == 128) glds16(Asrc + (size_t)64 * K + k0 + c * 32, &As[buf][c][srow + 64][schk]);
            glds16(Bsrc + k0 + c * 32, &Bs[buf][c][srow][schk]);
            if (BN == 128) glds16(Bsrc + (size_t)64 * K + k0 + c * 32, &Bs[buf][c][srow + 64][schk]);
        }
    };

    stage(0, 0);
    __syncthreads();

    for (int t = 0; t < nk; ++t) {
        const int buf = t & 1;
        if (t + 1 < nk) stage(buf ^ 1, (t + 1) * BK);
        #pragma unroll
        for (int kk = 0; kk < KC; ++kk) {
            bfrag af[MI], bf[NI];
            #pragma unroll
            for (int i = 0; i < MI; ++i)
                af[i] = *(const bfrag*)&As[buf][kk][rowb + i * 16 + r][g * 8];
            #pragma unroll
            for (int j = 0; j < NI; ++j)
                bf[j] = *(const bfrag*)&Bs[buf][kk][colb + j * 16 + r][g * 8];
            #pragma unroll
            for (int i = 0; i < MI; ++i)
                #pragma unroll
                for (int j = 0; j < NI; ++j)
                    acc[i][j] = __builtin_amdgcn_mfma_f32_16x16x32_bf16(af[i], bf[j], acc[i][j], 0, 0, 0);
        }
        __syncthreads();
    }

    #pragma unroll
    for (int i = 0; i < MI; ++i) {
        int row = row0 + rowb + i * 16 + g * 4;
        #pragma unroll
        for (int j = 0; j < NI; ++j) {
            int col = col0 + colb + j * 16 + r;
            #pragma unroll
            for (int q = 0; q < 4; ++q) {
                float v = acc[i][j][q];
                if (OUT_BF16) ((short*)Cout)[(size_t)(row + q) * N + col] = f2bf(v);
                else          ((float*)Cout)[(size_t)(row + q) * N + col] = v;
            }
        }
    }
}

// Fused KV GEMM with RoPE + Kr/Vb layout epilogue. XCD-swizzled (512 blocks).
// KV[4096 x 512] = hs(f32) @ Wt^T (Wt bf16, 512 x 2048), K=2048.
// A staged as f32 via global_load_lds with SOURCE-side XOR swizzle.
__global__ __launch_bounds__(256)
void kv_gemm(const float* __restrict__ A, const short* __restrict__ Bt,
             const float* __restrict__ tab, short* __restrict__ Kr,
             short* __restrict__ Vb) {
    constexpr int K = 2048;
    __shared__ float Af[2][64][64];     // 32 KB
    __shared__ short Bs[2][2][64][32];  // 16 KB
    const int tid = threadIdx.x;
    const int wv = tid >> 6, lane = tid & 63;
    const int g = lane >> 4, r = lane & 15;
    const int rowb = wv * 16;

    int bx = blockIdx.x, by = blockIdx.y;
    {
        int nwg = gridDim.x * gridDim.y;       // 512
        int bid = by * gridDim.x + bx;
        int cpx = nwg >> 3;
        int sid = (bid & 7) * cpx + (bid >> 3);
        bx = sid % gridDim.x;
        by = sid / gridDim.x;
    }
    const int row0 = by * 64;
    const int col0 = bx * 64;

    f32x4 acc[4];
    #pragma unroll
    for (int j = 0; j < 4; ++j) { f32x4 z = {0.f,0.f,0.f,0.f}; acc[j] = z; }

    const int arow_ = tid >> 4;          // row within quarter (0..15)
    const int sir_  = tid & 15;          // lds 16B-slot within row
    const int srow = tid >> 2;
    const int schk = (tid & 3) * 8;
    const short* Bsrc = Bt + (size_t)(col0 + srow) * K + schk;

    const int nk = K / 64;               // 32 iterations

    auto stage = [&](int buf, int k0) {
        #pragma unroll
        for (int q = 0; q < 4; ++q) {
            int row = q * 16 + arow_;
            int gslot = sir_ ^ (row & 15);
            glds16((const short*)(A + (size_t)(row0 + row) * K + k0 + gslot * 4),
                   (short*)&Af[buf][row][sir_ * 4]);
        }
        glds16(Bsrc + k0,      &Bs[buf][0][srow][schk]);
        glds16(Bsrc + k0 + 32, &Bs[buf][1][srow][schk]);
    };

    stage(0, 0);
    __syncthreads();

    for (int t = 0; t < nk; ++t) {
        const int buf = t & 1;
        if (t + 1 < nk) stage(buf ^ 1, (t + 1) * 64);
        #pragma unroll
        for (int kk = 0; kk < 2; ++kk) {
            const int s0 = kk * 8 + g * 2;
            const float* aprow = &Af[buf][rowb + r][0];
            f32x4 w0 = *(const f32x4*)(aprow + ((s0 ^ r) * 4));
            f32x4 w1 = *(const f32x4*)(aprow + (((s0 + 1) ^ r) * 4));
            u32x4 U = { cvtpk(w0[0], w0[1]), cvtpk(w0[2], w0[3]),
                        cvtpk(w1[0], w1[1]), cvtpk(w1[2], w1[3]) };
            bfrag af = __builtin_bit_cast(bfrag, U);
            bfrag bf[4];
            #pragma unroll
            for (int j = 0; j < 4; ++j) bf[j] = *(const bfrag*)&Bs[buf][kk][j * 16 + r][g * 8];
            #pragma unroll
            for (int j = 0; j < 4; ++j)
                acc[j] = __builtin_amdgcn_mfma_f32_16x16x32_bf16(af, bf[j], acc[j], 0, 0, 0);
        }
        __syncthreads();
    }

    const int kvh = bx >> 1;
    const bool isV = bx & 1;
    #pragma unroll
    for (int qq = 0; qq < 4; ++qq) {
        int row = row0 + rowb + g * 4 + qq;
        int b = row >> 11, s = row & (S_ - 1);
        if (!isV) {
            int swz = (s & 7) << 3;
            size_t base = ((size_t)(b * NKV_ + kvh) * S_ + s) * 64;
            const float* ct = tab + (size_t)s * 64;
            #pragma unroll
            for (int j = 0; j < 2; ++j) {
                int d = j * 16 + r;            // < 32
                float c = ct[d], sn = ct[32 + d];
                float k1 = acc[j][qq], k2 = acc[j + 2][qq];
                Kr[base + (d ^ swz)]        = f2bf(k1 * c - k2 * sn);
                Kr[base + ((d + 32) ^ swz)] = f2bf(k2 * c + k1 * sn);
            }
        } else {
            int kvl = s & 63, kt = s >> 6;
            int cc = (kvl & 3) | (((kvl >> 4) & 1) << 2) | (((kvl >> 2) & 3) << 3) | (kvl & 32);
            short* dst = Vb + ((size_t)((b * NKV_ + kvh) * 32 + kt)) * 4096;
            #pragma unroll
            for (int j = 0; j < 4; ++j) {
                int d = j * 16 + r;
                dst[d * 64 + (cc ^ ((d & 7) << 3))] = f2bf(acc[j][qq]);
            }
        }
    }
}

// Flash attention, swapped-QK^T bf16 MFMA, double-buffered K/V, KVBLK=64.
// DUAL-HEAD + DUAL-SUBTILE: 256 threads = 2 head-groups x 2 waves; each wave
// owns 32 q rows (2 x 16 subtiles) so every K/V fragment ds_read feeds TWO
// MFMA sets (halves LDS fragment traffic per q-row). One shared K/V LDS image
// per block. Block bx does chunks qc=bx then 31-bx (balanced).
// Softmax log2-domain; defer-max; l on MFMA pipe via ones-B.
__global__ __launch_bounds__(256)
void attn_mfma(const float* __restrict__ hs, const float* __restrict__ tab,
               const short* __restrict__ Kr, const short* __restrict__ Vb,
               short* __restrict__ AO) {
    const int bx = blockIdx.x, b = blockIdx.z;
    const int tid = threadIdx.x;
    const int hh = tid >> 7;                 // head-group 0/1
    const int wv = (tid >> 6) & 1;           // wave within group (32 q rows)
    const int lane = tid & 63, g = lane >> 4, r = lane & 15;
    const int h = (int)blockIdx.y * 2 + hh;
    const int kvh = h >> 3;                  // same for both groups

    __shared__ short Ks[2][4096];
    __shared__ short Vs[2][4096];

    const short* ksrc = Kr + ((size_t)(b * NKV_ + kvh)) * S_ * 64;
    const short* vsrc = Vb + ((size_t)(b * NKV_ + kvh)) * 32 * 4096;

    bfrag onesf;
    #pragma unroll
    for (int j = 0; j < 8; ++j) onesf[j] = (short)0x3F80;   // bf16 1.0

    #pragma unroll 1
    for (int pass = 0; pass < 2; ++pass) {
        const int qc = pass ? (31 - bx) : bx;      // 64-row chunk, 0..31
        const int base_w = qc * 64 + wv * 32;      // wave's 32-row window

        // Q fragments for both subtiles (RoPE + log2-domain scale folded)
        bfrag qf[2][2];
        #pragma unroll
        for (int u = 0; u < 2; ++u) {
            int q = base_w + u * 16 + r;
            const float* hq = hs + ((size_t)(b * S_ + q)) * HID_ + h * HD_;
            const float* ct = tab + (size_t)q * 64;
            float4 x1a = *(const float4*)(hq + g * 8);
            float4 x1b = *(const float4*)(hq + g * 8 + 4);
            float4 x2a = *(const float4*)(hq + 32 + g * 8);
            float4 x2b = *(const float4*)(hq + 32 + g * 8 + 4);
            float4 ca  = *(const float4*)(ct + g * 8);
            float4 cb  = *(const float4*)(ct + g * 8 + 4);
            float4 sa4 = *(const float4*)(ct + 32 + g * 8);
            float4 sb4 = *(const float4*)(ct + 32 + g * 8 + 4);
            float x1[8] = {x1a.x,x1a.y,x1a.z,x1a.w,x1b.x,x1b.y,x1b.z,x1b.w};
            float x2[8] = {x2a.x,x2a.y,x2a.z,x2a.w,x2b.x,x2b.y,x2b.z,x2b.w};
            float cc[8] = {ca.x,ca.y,ca.z,ca.w,cb.x,cb.y,cb.z,cb.w};
            float ss[8] = {sa4.x,sa4.y,sa4.z,sa4.w,sb4.x,sb4.y,sb4.z,sb4.w};
            #pragma unroll
            for (int j = 0; j < 8; ++j) {
                qf[u][0][j] = f2bf((x1[j] * cc[j] - x2[j] * ss[j]) * QSCALE);
                qf[u][1][j] = f2bf((x2[j] * cc[j] + x1[j] * ss[j]) * QSCALE);
            }
        }

        f32x4 oacc[2][4];
        f32x4 lacc[2];
        float m[2];
        #pragma unroll
        for (int u = 0; u < 2; ++u) {
            #pragma unroll
            for (int i = 0; i < 4; ++i) { f32x4 z = {0.f,0.f,0.f,0.f}; oacc[u][i] = z; }
            f32x4 z = {0.f,0.f,0.f,0.f}; lacc[u] = z;
            m[u] = NEGV;
        }

        const int ntile = qc + 1;

        // prologue: stage tile 0 into buf 0 (256 thr x 2 x 16B per array)
        glds16(ksrc + (size_t)0 + tid * 8,    &Ks[0][tid * 8]);
        glds16(ksrc + (size_t)2048 + tid * 8, &Ks[0][2048 + tid * 8]);
        glds16(vsrc + (size_t)0 + tid * 8,    &Vs[0][tid * 8]);
        glds16(vsrc + (size_t)2048 + tid * 8, &Vs[0][2048 + tid * 8]);
        __syncthreads();

        #pragma unroll 1
        for (int kt = 0; kt < ntile; ++kt) {
            const int k0 = kt * 64;
            const int buf = kt & 1;
            if (kt + 1 < ntile) {
                const size_t nb = (size_t)(kt + 1) * 4096;
                glds16(ksrc + nb + tid * 8,        &Ks[buf ^ 1][tid * 8]);
                glds16(ksrc + nb + 2048 + tid * 8, &Ks[buf ^ 1][2048 + tid * 8]);
                glds16(vsrc + nb + tid * 8,        &Vs[buf ^ 1][tid * 8]);
                glds16(vsrc + nb + 2048 + tid * 8, &Vs[buf ^ 1][2048 + tid * 8]);
            }

            const bool do0 = (k0 <= base_w + 15);        // subtile 0 live
            const bool do1 = (k0 <= base_w + 31);        // subtile 1 live
            if (do1) {
                const int lim0 = (base_w + 15 - k0) >> 4;
                const int lim1 = (base_w + 31 - k0) >> 4;

                // QK^T: shared K fragment reads feed both subtiles
                f32x4 sa[2][4];
                __builtin_amdgcn_s_setprio(1);
                #pragma unroll
                for (int nt = 0; nt < 4; ++nt) {
                    f32x4 nz = {NEGV, NEGV, NEGV, NEGV};
                    if (nt <= lim1) {
                        int row = nt * 16 + r;
                        int sw = (row & 7) << 3;
                        bfrag kf0 = *(const bfrag*)&Ks[buf][row * 64 + ((g * 8) ^ sw)];
                        bfrag kf1 = *(const bfrag*)&Ks[buf][row * 64 + ((32 + g * 8) ^ sw)];
                        f32x4 z1 = {0.f,0.f,0.f,0.f};
                        z1 = __builtin_amdgcn_mfma_f32_16x16x32_bf16(kf0, qf[1][0], z1, 0, 0, 0);
                        z1 = __builtin_amdgcn_mfma_f32_16x16x32_bf16(kf1, qf[1][1], z1, 0, 0, 0);
                        sa[1][nt] = z1;
                        if (do0 && nt <= lim0) {
                            f32x4 z0 = {0.f,0.f,0.f,0.f};
                            z0 = __builtin_amdgcn_mfma_f32_16x16x32_bf16(kf0, qf[0][0], z0, 0, 0, 0);
                            z0 = __builtin_amdgcn_mfma_f32_16x16x32_bf16(kf1, qf[0][1], z0, 0, 0, 0);
                            sa[0][nt] = z0;
                        } else sa[0][nt] = nz;
                    } else { sa[1][nt] = nz; sa[0][nt] = nz; }
                }
                __builtin_amdgcn_s_setprio(0);

                // per-subtile softmax + P-pack (skip dead subtile 0 entirely)
                bfrag pa[2][2];
                #pragma unroll
                for (int u = 0; u < 2; ++u) {
                    if (u == 0 && !do0) continue;
                    const int qbu = base_w + u * 16;
                    const int qg = qbu + r;
                    if (k0 + 63 > qbu) {
                        #pragma unroll
                        for (int nt = 0; nt < 4; ++nt)
                            #pragma unroll
                            for (int p = 0; p < 4; ++p) {
                                int kvg = k0 + nt * 16 + 4 * g + p;
                                if (kvg > qg) sa[u][nt][p] = NEGV;
                            }
                    }
                    float a0 = fmax3(sa[u][0][0], sa[u][0][1], sa[u][0][2]);
                    float a1 = fmax3(sa[u][0][3], sa[u][1][0], sa[u][1][1]);
                    float a2 = fmax3(sa[u][1][2], sa[u][1][3], sa[u][2][0]);
                    float a3 = fmax3(sa[u][2][1], sa[u][2][2], sa[u][2][3]);
                    float a4 = fmax3(sa[u][3][0], sa[u][3][1], sa[u][3][2]);
                    float tm = fmax3(fmax3(a0, a1, sa[u][3][3]), fmaxf(a2, a3), a4);
                    const bool need = __any(tm > m[u] + THR_);
                    if (need) {
                        float t2 = fmaxf(tm, __shfl_xor(tm, 16, 64));
                        t2 = fmaxf(t2, __shfl_xor(t2, 32, 64));
                        float mn = fmaxf(m[u], t2);
                        float cf = ex2(m[u] - mn);
                        m[u] = mn;
                        float cfp[4];
                        #pragma unroll
                        for (int p = 0; p < 4; ++p) cfp[p] = __shfl(cf, 20 * g + p, 64);
                        #pragma unroll
                        for (int p = 0; p < 4; ++p) {
                            lacc[u][p] *= cfp[p];
                            #pragma unroll
                            for (int nt = 0; nt < 4; ++nt) oacc[u][nt][p] *= cfp[p];
                        }
                    }
                    #pragma unroll
                    for (int nt = 0; nt < 4; ++nt)
                        #pragma unroll
                        for (int p = 0; p < 4; ++p)
                            sa[u][nt][p] = ex2(sa[u][nt][p] - m[u]);
                    u32x4 U0 = { cvtpk(sa[u][0][0], sa[u][0][1]), cvtpk(sa[u][0][2], sa[u][0][3]),
                                 cvtpk(sa[u][1][0], sa[u][1][1]), cvtpk(sa[u][1][2], sa[u][1][3]) };
                    u32x4 U1 = { cvtpk(sa[u][2][0], sa[u][2][1]), cvtpk(sa[u][2][2], sa[u][2][3]),
                                 cvtpk(sa[u][3][0], sa[u][3][1]), cvtpk(sa[u][3][2], sa[u][3][3]) };
                    pa[u][0] = __builtin_bit_cast(bfrag, U0);
                    pa[u][1] = __builtin_bit_cast(bfrag, U1);
                }

                // PV + l-accum: shared V fragment reads feed both subtiles
                const bool do0b = do0 && (lim0 >= 2);
                __builtin_amdgcn_s_setprio(1);
                lacc[1] = __builtin_amdgcn_mfma_f32_16x16x32_bf16(pa[1][0], onesf, lacc[1], 0, 0, 0);
                if (do0)
                    lacc[0] = __builtin_amdgcn_mfma_f32_16x16x32_bf16(pa[0][0], onesf, lacc[0], 0, 0, 0);
                #pragma unroll
                for (int nt = 0; nt < 4; ++nt) {
                    int row = nt * 16 + r;
                    int sw = (row & 7) << 3;
                    bfrag vf0 = *(const bfrag*)&Vs[buf][row * 64 + ((g * 8) ^ sw)];
                    oacc[1][nt] = __builtin_amdgcn_mfma_f32_16x16x32_bf16(pa[1][0], vf0, oacc[1][nt], 0, 0, 0);
                    if (do0)
                        oacc[0][nt] = __builtin_amdgcn_mfma_f32_16x16x32_bf16(pa[0][0], vf0, oacc[0][nt], 0, 0, 0);
                }
                if (lim1 >= 2) {
                    lacc[1] = __builtin_amdgcn_mfma_f32_16x16x32_bf16(pa[1][1], onesf, lacc[1], 0, 0, 0);
                    if (do0b)
                        lacc[0] = __builtin_amdgcn_mfma_f32_16x16x32_bf16(pa[0][1], onesf, lacc[0], 0, 0, 0);
                    #pragma unroll
                    for (int nt = 0; nt < 4; ++nt) {
                        int row = nt * 16 + r;
                        int sw = (row & 7) << 3;
                        bfrag vf1 = *(const bfrag*)&Vs[buf][row * 64 + ((32 + g * 8) ^ sw)];
                        oacc[1][nt] = __builtin_amdgcn_mfma_f32_16x16x32_bf16(pa[1][1], vf1, oacc[1][nt], 0, 0, 0);
                        if (do0b)
                            oacc[0][nt] = __builtin_amdgcn_mfma_f32_16x16x32_bf16(pa[0][1], vf1, oacc[0][nt], 0, 0, 0);
                    }
                }
                __builtin_amdgcn_s_setprio(0);
            }
            __syncthreads();
        }

        #pragma unroll
        for (int u = 0; u < 2; ++u) {
            #pragma unroll
            for (int p = 0; p < 4; ++p) {
                float inv = 1.f / lacc[u][p];
                int qrow = base_w + u * 16 + 4 * g + p;
                short* op = AO + ((size_t)(b * S_ + qrow)) * (NH_ * HD_) + h * HD_;
                #pragma unroll
                for (int nt = 0; nt < 4; ++nt)
                    op[nt * 16 + r] = f2bf(oacc[u][nt][p] * inv);
            }
        }
    }
}

extern "C" void kernel_launch(void* const* d_in, const int* in_sizes, int n_in,
                              void* d_out, int out_size, void* d_ws, size_t ws_size,
                              hipStream_t stream) {
    const float* hs   = (const float*)d_in[0];
    const float* kv_a = (const float*)d_in[1];
    const float* kv_b = (const float*)d_in[2];
    const float* o_w  = (const float*)d_in[3];
    float* out = (float*)d_out;
    char* w = (char*)d_ws;

    float* tab    = (float*)w;                w += 524288;       // 2048*64 f32
    short* AO     = (short*)w;                w += 16777216;     // 4096 x 2048 bf16
    short* kva_bf = (short*)w;                w += 2097152;      // 2048 x 512 bf16
    short* kvbT   = (short*)w;                w += 524288;       // 512 x 512 bf16
    short* owT    = (short*)w;                w += 8388608;      // 2048 x 2048 bf16
    short* Wt     = (short*)w;                w += 2097152;      // 512 x 2048 bf16
    short* Kr     = (short*)w;                w += 2097152;      // 2*4*2048*64 bf16
    short* Vb     = (short*)w;                w += 2097152;

    rope_table_k<<<dim3(256), dim3(256), 0, stream>>>(tab);
    f2b_k<<<dim3(1024), dim3(256), 0, stream>>>(kv_a, kva_bf);     // 2048x512

    transpose_f2b<<<dim3(16, 16), dim3(32, 8), 0, stream>>>(kv_b, kvbT, 512, 512);
    transpose_f2b<<<dim3(64, 64), dim3(32, 8), 0, stream>>>(o_w, owT, 2048, 2048);

    // Wt = (kv_a @ kv_b)^T = kvbT @ kvaT, via mgemm(A=kvbT, Bt=kva_bf)
    mgemm<64,64,64,true,false><<<dim3(32, 8), dim3(256), 0, stream>>>(kvbT, kva_bf, Wt, 512, 2048, 512);

    // Fused: KV = hs(f32) @ W, K=2048, RoPE + Kr/Vb epilogue (XCD-swizzled)
    kv_gemm<<<dim3(8, 64), dim3(256), 0, stream>>>(hs, Wt, tab, Kr, Vb);

    // dual-head dual-subtile GQA attention: grid (16, 16 head-pairs, B), 256 thr
    attn_mfma<<<dim3(16, 16, 2), dim3(256), 0, stream>>>(hs, tab, Kr, Vb, AO);

    // out-proj: 128x128 tile, BK=64, XCD-swizzled -> grid (16, 32)
    mgemm<128,128,64,false,true><<<dim3(16, 32), dim3(256), 0, stream>>>(AO, owT, out, 4096, 2048, 2048);
}

// Round 25
// 152.082 us; speedup vs baseline: 1.1127x; 1.1127x over previous
//
#include <hip/hip_runtime.h>
#include <hip/hip_bf16.h>
#include <math.h>

#define B_    2
#define S_    2048
#define HID_  2048
#define NH_   32
#define NKV_  4
#define HD_   64
#define NEGV  (-1e30f)
#define QSCALE 0.1803368802f   /* 0.125 * log2(e) */
#define THR_  11.5f            /* defer-max threshold, log2 units (~e^8) */

typedef __attribute__((ext_vector_type(8))) short bfrag;
typedef __attribute__((ext_vector_type(4))) float f32x4;
typedef __attribute__((ext_vector_type(4))) unsigned u32x4;

__device__ __forceinline__ float ex2(float x) {
    return __builtin_amdgcn_exp2f(x);      // raw v_exp_f32 (2^x)
}

__device__ __forceinline__ float fmax3(float a, float b, float c) {
    return fmaxf(fmaxf(a, b), c);          // clang fuses to v_max3_f32
}

__device__ __forceinline__ short f2bf(float f) {
    unsigned u = __builtin_bit_cast(unsigned, f);
    u += 0x7FFFu + ((u >> 16) & 1u);
    return (short)(u >> 16);
}

__device__ __forceinline__ unsigned cvtpk(float lo, float hi) {
    unsigned w;
    asm("v_cvt_pk_bf16_f32 %0, %1, %2" : "=v"(w) : "v"(lo), "v"(hi));
    return w;
}

__device__ __forceinline__ void glds16(const short* g, short* l) {
    __builtin_amdgcn_global_load_lds(
        (const __attribute__((address_space(1))) void*)(const void*)g,
        (__attribute__((address_space(3))) void*)(void*)l, 16, 0, 0);
}

// cos/sin table: tab[s*64+i]=cos, tab[s*64+32+i]=sin
__global__ void rope_table_k(float* __restrict__ tab) {
    int idx = blockIdx.x * blockDim.x + threadIdx.x;
    if (idx >= S_ * 32) return;
    int s = idx >> 5, i = idx & 31;
    float inv = 1.0f / powf(10000.0f, (float)(2 * i) / 64.0f);
    float ang = (float)s * inv;
    tab[s * 64 + i]      = cosf(ang);
    tab[s * 64 + 32 + i] = sinf(ang);
}

__global__ void f2b_k(const float* __restrict__ in, short* __restrict__ out) {
    int i = (blockIdx.x * blockDim.x + threadIdx.x) * 4;
    float4 v = *(const float4*)(in + i);
    short4 o;
    o.x = f2bf(v.x); o.y = f2bf(v.y); o.z = f2bf(v.z); o.w = f2bf(v.w);
    *(short4*)(out + i) = o;
}

// fp32 (R x C) -> bf16 transposed (C x R)
__global__ void transpose_f2b(const float* __restrict__ in, short* __restrict__ out,
                              int R, int C) {
    __shared__ float t[32][33];
    int c0 = blockIdx.x * 32, r0 = blockIdx.y * 32;
    int x = threadIdx.x, y = threadIdx.y;  // 32 x 8
    #pragma unroll
    for (int i = 0; i < 32; i += 8) t[y + i][x] = in[(size_t)(r0 + y + i) * C + c0 + x];
    __syncthreads();
    #pragma unroll
    for (int i = 0; i < 32; i += 8)
        out[(size_t)(c0 + y + i) * R + r0 + x] = f2bf(t[x][y + i]);
}

// bf16 MFMA GEMM: C[M,N] = A[M,K] @ Bt[N,K]^T. BM x BN tile, BK in {32,64}.
// LDS stored as [2][BK/32][rows][32] so every 32-k chunk keeps the lane-linear
// global_load_lds layout. SWZ: bijective XCD-aware block swizzle (nwg%8==0).
template<int BM, int BN, int BK, bool OUT_BF16, bool SWZ>
__global__ __launch_bounds__(256)
void mgemm(const short* __restrict__ A, const short* __restrict__ Bt,
           void* __restrict__ Cout, int M, int N, int K) {
    constexpr int KC = BK / 32;
    __shared__ short As[2][KC][BM][32];
    __shared__ short Bs[2][KC][BN][32];
    const int tid = threadIdx.x;
    const int wv = tid >> 6, lane = tid & 63;
    const int g = lane >> 4, r = lane & 15;
    constexpr int MI = (BM == 128 && BN == 128) ? 4 : (BM == 128 ? 2 : 1);
    constexpr int NI = 4;
    const int rowb = (BM == 128 && BN == 128) ? (wv >> 1) * 64
                   : (BM == 128 ? wv * 32 : wv * 16);
    const int colb = (BM == 128 && BN == 128) ? (wv & 1) * 64 : 0;

    int bx = blockIdx.x, by = blockIdx.y;
    if (SWZ) {
        int nwg = gridDim.x * gridDim.y;
        int bid = by * gridDim.x + bx;
        int cpx = nwg >> 3;
        int sid = (bid & 7) * cpx + (bid >> 3);
        bx = sid % gridDim.x;
        by = sid / gridDim.x;
    }
    const int row0 = by * BM;
    const int col0 = bx * BN;

    f32x4 acc[MI][NI];
    #pragma unroll
    for (int i = 0; i < MI; ++i)
        #pragma unroll
        for (int j = 0; j < NI; ++j) { f32x4 z = {0.f,0.f,0.f,0.f}; acc[i][j] = z; }

    const int srow = tid >> 2;          // 0..63
    const int schk = (tid & 3) * 8;     // 0,8,16,24
    const short* Asrc = A + (size_t)(row0 + srow) * K + schk;
    const short* Bsrc = Bt + (size_t)(col0 + srow) * K + schk;

    const int nk = K / BK;

    auto stage = [&](int buf, int k0) {
        #pragma unroll
        for (int c = 0; c < KC; ++c) {
            glds16(Asrc + k0 + c * 32, &As[buf][c][srow][schk]);
            if (BM == 128) glds16(Asrc + (size_t)64 * K + k0 + c * 32, &As[buf][c][srow + 64][schk]);
            glds16(Bsrc + k0 + c * 32, &Bs[buf][c][srow][schk]);
            if (BN == 128) glds16(Bsrc + (size_t)64 * K + k0 + c * 32, &Bs[buf][c][srow + 64][schk]);
        }
    };

    stage(0, 0);
    __syncthreads();

    for (int t = 0; t < nk; ++t) {
        const int buf = t & 1;
        if (t + 1 < nk) stage(buf ^ 1, (t + 1) * BK);
        #pragma unroll
        for (int kk = 0; kk < KC; ++kk) {
            bfrag af[MI], bf[NI];
            #pragma unroll
            for (int i = 0; i < MI; ++i)
                af[i] = *(const bfrag*)&As[buf][kk][rowb + i * 16 + r][g * 8];
            #pragma unroll
            for (int j = 0; j < NI; ++j)
                bf[j] = *(const bfrag*)&Bs[buf][kk][colb + j * 16 + r][g * 8];
            #pragma unroll
            for (int i = 0; i < MI; ++i)
                #pragma unroll
                for (int j = 0; j < NI; ++j)
                    acc[i][j] = __builtin_amdgcn_mfma_f32_16x16x32_bf16(af[i], bf[j], acc[i][j], 0, 0, 0);
        }
        __syncthreads();
    }

    #pragma unroll
    for (int i = 0; i < MI; ++i) {
        int row = row0 + rowb + i * 16 + g * 4;
        #pragma unroll
        for (int j = 0; j < NI; ++j) {
            int col = col0 + colb + j * 16 + r;
            #pragma unroll
            for (int q = 0; q < 4; ++q) {
                float v = acc[i][j][q];
                if (OUT_BF16) ((short*)Cout)[(size_t)(row + q) * N + col] = f2bf(v);
                else          ((float*)Cout)[(size_t)(row + q) * N + col] = v;
            }
        }
    }
}

// Fused KV GEMM with RoPE + Kr/Vb layout epilogue. XCD-swizzled (512 blocks).
// KV[4096 x 512] = hs(f32) @ Wt^T (Wt bf16, 512 x 2048), K=2048.
// A staged as f32 via global_load_lds with SOURCE-side XOR swizzle.
__global__ __launch_bounds__(256)
void kv_gemm(const float* __restrict__ A, const short* __restrict__ Bt,
             const float* __restrict__ tab, short* __restrict__ Kr,
             short* __restrict__ Vb) {
    constexpr int K = 2048;
    __shared__ float Af[2][64][64];     // 32 KB
    __shared__ short Bs[2][2][64][32];  // 16 KB
    const int tid = threadIdx.x;
    const int wv = tid >> 6, lane = tid & 63;
    const int g = lane >> 4, r = lane & 15;
    const int rowb = wv * 16;

    int bx = blockIdx.x, by = blockIdx.y;
    {
        int nwg = gridDim.x * gridDim.y;       // 512
        int bid = by * gridDim.x + bx;
        int cpx = nwg >> 3;
        int sid = (bid & 7) * cpx + (bid >> 3);
        bx = sid % gridDim.x;
        by = sid / gridDim.x;
    }
    const int row0 = by * 64;
    const int col0 = bx * 64;

    f32x4 acc[4];
    #pragma unroll
    for (int j = 0; j < 4; ++j) { f32x4 z = {0.f,0.f,0.f,0.f}; acc[j] = z; }

    const int arow_ = tid >> 4;          // row within quarter (0..15)
    const int sir_  = tid & 15;          // lds 16B-slot within row
    const int srow = tid >> 2;
    const int schk = (tid & 3) * 8;
    const short* Bsrc = Bt + (size_t)(col0 + srow) * K + schk;

    const int nk = K / 64;               // 32 iterations

    auto stage = [&](int buf, int k0) {
        #pragma unroll
        for (int q = 0; q < 4; ++q) {
            int row = q * 16 + arow_;
            int gslot = sir_ ^ (row & 15);
            glds16((const short*)(A + (size_t)(row0 + row) * K + k0 + gslot * 4),
                   (short*)&Af[buf][row][sir_ * 4]);
        }
        glds16(Bsrc + k0,      &Bs[buf][0][srow][schk]);
        glds16(Bsrc + k0 + 32, &Bs[buf][1][srow][schk]);
    };

    stage(0, 0);
    __syncthreads();

    for (int t = 0; t < nk; ++t) {
        const int buf = t & 1;
        if (t + 1 < nk) stage(buf ^ 1, (t + 1) * 64);
        #pragma unroll
        for (int kk = 0; kk < 2; ++kk) {
            const int s0 = kk * 8 + g * 2;
            const float* aprow = &Af[buf][rowb + r][0];
            f32x4 w0 = *(const f32x4*)(aprow + ((s0 ^ r) * 4));
            f32x4 w1 = *(const f32x4*)(aprow + (((s0 + 1) ^ r) * 4));
            u32x4 U = { cvtpk(w0[0], w0[1]), cvtpk(w0[2], w0[3]),
                        cvtpk(w1[0], w1[1]), cvtpk(w1[2], w1[3]) };
            bfrag af = __builtin_bit_cast(bfrag, U);
            bfrag bf[4];
            #pragma unroll
            for (int j = 0; j < 4; ++j) bf[j] = *(const bfrag*)&Bs[buf][kk][j * 16 + r][g * 8];
            #pragma unroll
            for (int j = 0; j < 4; ++j)
                acc[j] = __builtin_amdgcn_mfma_f32_16x16x32_bf16(af, bf[j], acc[j], 0, 0, 0);
        }
        __syncthreads();
    }

    const int kvh = bx >> 1;
    const bool isV = bx & 1;
    #pragma unroll
    for (int qq = 0; qq < 4; ++qq) {
        int row = row0 + rowb + g * 4 + qq;
        int b = row >> 11, s = row & (S_ - 1);
        if (!isV) {
            int swz = (s & 7) << 3;
            size_t base = ((size_t)(b * NKV_ + kvh) * S_ + s) * 64;
            const float* ct = tab + (size_t)s * 64;
            #pragma unroll
            for (int j = 0; j < 2; ++j) {
                int d = j * 16 + r;            // < 32
                float c = ct[d], sn = ct[32 + d];
                float k1 = acc[j][qq], k2 = acc[j + 2][qq];
                Kr[base + (d ^ swz)]        = f2bf(k1 * c - k2 * sn);
                Kr[base + ((d + 32) ^ swz)] = f2bf(k2 * c + k1 * sn);
            }
        } else {
            int kvl = s & 63, kt = s >> 6;
            int cc = (kvl & 3) | (((kvl >> 4) & 1) << 2) | (((kvl >> 2) & 3) << 3) | (kvl & 32);
            short* dst = Vb + ((size_t)((b * NKV_ + kvh) * 32 + kt)) * 4096;
            #pragma unroll
            for (int j = 0; j < 4; ++j) {
                int d = j * 16 + r;
                dst[d * 64 + (cc ^ ((d & 7) << 3))] = f2bf(acc[j][qq]);
            }
        }
    }
}

// Flash attention, swapped-QK^T bf16 MFMA, double-buffered K/V, KVBLK=64.
// DUAL-HEAD GQA blocks (512 thr = 2 head-groups x 4 waves) sharing one K/V
// LDS image. Block bx does chunks qc=bx then 31-bx (33 tiles, balanced).
// Softmax log2-domain; defer-max; l accumulated on the MFMA pipe via
// ones-B fragment (lacc[p] = sum_kv P[q=4g+p], oacc-layout, no shuffles).
__global__ __launch_bounds__(512)
void attn_mfma(const float* __restrict__ hs, const float* __restrict__ tab,
               const short* __restrict__ Kr, const short* __restrict__ Vb,
               short* __restrict__ AO) {
    const int bx = blockIdx.x, b = blockIdx.z;
    const int tid = threadIdx.x;
    const int hh = tid >> 8;                 // head-group 0/1
    const int wv = (tid >> 6) & 3;           // wave within head-group
    const int lane = tid & 63, g = lane >> 4, r = lane & 15;
    const int h = (int)blockIdx.y * 2 + hh;
    const int kvh = h >> 3;                  // same for both groups

    __shared__ short Ks[2][4096];
    __shared__ short Vs[2][4096];

    const short* ksrc = Kr + ((size_t)(b * NKV_ + kvh)) * S_ * 64;
    const short* vsrc = Vb + ((size_t)(b * NKV_ + kvh)) * 32 * 4096;

    bfrag onesf;
    #pragma unroll
    for (int j = 0; j < 8; ++j) onesf[j] = (short)0x3F80;   // bf16 1.0

    #pragma unroll 1
    for (int pass = 0; pass < 2; ++pass) {
        const int qc = pass ? (31 - bx) : bx;      // 64-row chunk, 0..31
        const int qbase = qc * 64 + wv * 16;

        // Q fragments (RoPE + log2-domain scale folded)
        bfrag qf0, qf1;
        {
            int q = qbase + r;
            const float* hq = hs + ((size_t)(b * S_ + q)) * HID_ + h * HD_;
            const float* ct = tab + (size_t)q * 64;
            float4 x1a = *(const float4*)(hq + g * 8);
            float4 x1b = *(const float4*)(hq + g * 8 + 4);
            float4 x2a = *(const float4*)(hq + 32 + g * 8);
            float4 x2b = *(const float4*)(hq + 32 + g * 8 + 4);
            float4 ca  = *(const float4*)(ct + g * 8);
            float4 cb  = *(const float4*)(ct + g * 8 + 4);
            float4 sa4 = *(const float4*)(ct + 32 + g * 8);
            float4 sb4 = *(const float4*)(ct + 32 + g * 8 + 4);
            float x1[8] = {x1a.x,x1a.y,x1a.z,x1a.w,x1b.x,x1b.y,x1b.z,x1b.w};
            float x2[8] = {x2a.x,x2a.y,x2a.z,x2a.w,x2b.x,x2b.y,x2b.z,x2b.w};
            float cc[8] = {ca.x,ca.y,ca.z,ca.w,cb.x,cb.y,cb.z,cb.w};
            float ss[8] = {sa4.x,sa4.y,sa4.z,sa4.w,sb4.x,sb4.y,sb4.z,sb4.w};
            #pragma unroll
            for (int j = 0; j < 8; ++j) {
                qf0[j] = f2bf((x1[j] * cc[j] - x2[j] * ss[j]) * QSCALE);
                qf1[j] = f2bf((x2[j] * cc[j] + x1[j] * ss[j]) * QSCALE);
            }
        }

        f32x4 oacc[4];
        #pragma unroll
        for (int i = 0; i < 4; ++i) { f32x4 z = {0.f,0.f,0.f,0.f}; oacc[i] = z; }
        f32x4 lacc = {0.f,0.f,0.f,0.f};
        float m = NEGV;

        const int ntile = qc + 1;

        // prologue: stage tile 0 into buf 0 (512 thr x 8B + 8B)
        glds16(ksrc + (size_t)0 + tid * 8, &Ks[0][tid * 8]);
        glds16(vsrc + (size_t)0 + tid * 8, &Vs[0][tid * 8]);
        __syncthreads();

        #pragma unroll 1
        for (int kt = 0; kt < ntile; ++kt) {
            const int k0 = kt * 64;
            const int buf = kt & 1;
            if (kt + 1 < ntile) {
                const size_t nb = (size_t)(kt + 1) * 4096;
                glds16(ksrc + nb + tid * 8, &Ks[buf ^ 1][tid * 8]);
                glds16(vsrc + nb + tid * 8, &Vs[buf ^ 1][tid * 8]);
            }

            // wave-uniform kv-subtile limit: nt > lim is fully masked (diagonal)
            const int lim = (qbase + 15 - k0) >> 4;       // >= 3 off-diagonal
            const int qg = qbase + r;

            // QK^T swapped: A=K rows(kv), B=Q cols(q)
            f32x4 sa[4];
            __builtin_amdgcn_s_setprio(1);
            #pragma unroll
            for (int nt = 0; nt < 4; ++nt) {
                if (nt <= lim) {
                    int row = nt * 16 + r;
                    int sw = (row & 7) << 3;
                    bfrag kf0 = *(const bfrag*)&Ks[buf][row * 64 + ((g * 8) ^ sw)];
                    bfrag kf1 = *(const bfrag*)&Ks[buf][row * 64 + ((32 + g * 8) ^ sw)];
                    f32x4 z = {0.f,0.f,0.f,0.f};
                    z = __builtin_amdgcn_mfma_f32_16x16x32_bf16(kf0, qf0, z, 0, 0, 0);
                    z = __builtin_amdgcn_mfma_f32_16x16x32_bf16(kf1, qf1, z, 0, 0, 0);
                    sa[nt] = z;
                } else {
                    f32x4 z = {NEGV, NEGV, NEGV, NEGV};
                    sa[nt] = z;
                }
            }
            __builtin_amdgcn_s_setprio(0);
            // causal mask (diagonal tile only)
            if (k0 + 63 > qbase) {
                #pragma unroll
                for (int nt = 0; nt < 4; ++nt) {
                    #pragma unroll
                    for (int p = 0; p < 4; ++p) {
                        int kvg = k0 + nt * 16 + 4 * g + p;
                        if (kvg > qg) sa[nt][p] = NEGV;
                    }
                }
            }
            // online softmax (log2 domain), defer-max; v_max3 tree
            float a0 = fmax3(sa[0][0], sa[0][1], sa[0][2]);
            float a1 = fmax3(sa[0][3], sa[1][0], sa[1][1]);
            float a2 = fmax3(sa[1][2], sa[1][3], sa[2][0]);
            float a3 = fmax3(sa[2][1], sa[2][2], sa[2][3]);
            float a4 = fmax3(sa[3][0], sa[3][1], sa[3][2]);
            float tm = fmax3(fmax3(a0, a1, sa[3][3]), fmaxf(a2, a3), a4);
            const bool need = __any(tm > m + THR_);
            if (need) {
                float t2 = fmaxf(tm, __shfl_xor(tm, 16, 64));
                t2 = fmaxf(t2, __shfl_xor(t2, 32, 64));
                float mn = fmaxf(m, t2);
                float cf = ex2(m - mn);
                m = mn;
                float cfp[4];
                #pragma unroll
                for (int p = 0; p < 4; ++p) cfp[p] = __shfl(cf, 20 * g + p, 64);
                #pragma unroll
                for (int p = 0; p < 4; ++p) {
                    lacc[p] *= cfp[p];
                    #pragma unroll
                    for (int nt = 0; nt < 4; ++nt) oacc[nt][p] *= cfp[p];
                }
            }
            #pragma unroll
            for (int nt = 0; nt < 4; ++nt)
                #pragma unroll
                for (int p = 0; p < 4; ++p)
                    sa[nt][p] = ex2(sa[nt][p] - m);
            // pack P into A-frags via v_cvt_pk_bf16_f32
            u32x4 U0, U1;
            U0[0] = cvtpk(sa[0][0], sa[0][1]);
            U0[1] = cvtpk(sa[0][2], sa[0][3]);
            U0[2] = cvtpk(sa[1][0], sa[1][1]);
            U0[3] = cvtpk(sa[1][2], sa[1][3]);
            U1[0] = cvtpk(sa[2][0], sa[2][1]);
            U1[1] = cvtpk(sa[2][2], sa[2][3]);
            U1[2] = cvtpk(sa[3][0], sa[3][1]);
            U1[3] = cvtpk(sa[3][2], sa[3][3]);
            bfrag pa0 = __builtin_bit_cast(bfrag, U0);
            bfrag pa1 = __builtin_bit_cast(bfrag, U1);
            // PV + l-accum via ones-B: lacc[p] += sum_kv P[q=4g+p][kv]
            __builtin_amdgcn_s_setprio(1);
            lacc = __builtin_amdgcn_mfma_f32_16x16x32_bf16(pa0, onesf, lacc, 0, 0, 0);
            #pragma unroll
            for (int nt = 0; nt < 4; ++nt) {
                int row = nt * 16 + r;
                int sw = (row & 7) << 3;
                bfrag vf0 = *(const bfrag*)&Vs[buf][row * 64 + ((g * 8) ^ sw)];
                oacc[nt] = __builtin_amdgcn_mfma_f32_16x16x32_bf16(pa0, vf0, oacc[nt], 0, 0, 0);
            }
            if (lim >= 2) {
                lacc = __builtin_amdgcn_mfma_f32_16x16x32_bf16(pa1, onesf, lacc, 0, 0, 0);
                #pragma unroll
                for (int nt = 0; nt < 4; ++nt) {
                    int row = nt * 16 + r;
                    int sw = (row & 7) << 3;
                    bfrag vf1 = *(const bfrag*)&Vs[buf][row * 64 + ((32 + g * 8) ^ sw)];
                    oacc[nt] = __builtin_amdgcn_mfma_f32_16x16x32_bf16(pa1, vf1, oacc[nt], 0, 0, 0);
                }
            }
            __builtin_amdgcn_s_setprio(0);
            __syncthreads();
        }

        #pragma unroll
        for (int p = 0; p < 4; ++p) {
            float inv = 1.f / lacc[p];
            int qrow = qbase + 4 * g + p;
            short* op = AO + ((size_t)(b * S_ + qrow)) * (NH_ * HD_) + h * HD_;
            #pragma unroll
            for (int nt = 0; nt < 4; ++nt)
                op[nt * 16 + r] = f2bf(oacc[nt][p] * inv);
        }
    }
}

extern "C" void kernel_launch(void* const* d_in, const int* in_sizes, int n_in,
                              void* d_out, int out_size, void* d_ws, size_t ws_size,
                              hipStream_t stream) {
    const float* hs   = (const float*)d_in[0];
    const float* kv_a = (const float*)d_in[1];
    const float* kv_b = (const float*)d_in[2];
    const float* o_w  = (const float*)d_in[3];
    float* out = (float*)d_out;
    char* w = (char*)d_ws;

    float* tab    = (float*)w;                w += 524288;       // 2048*64 f32
    short* AO     = (short*)w;                w += 16777216;     // 4096 x 2048 bf16
    short* kva_bf = (short*)w;                w += 2097152;      // 2048 x 512 bf16
    short* kvbT   = (short*)w;                w += 524288;       // 512 x 512 bf16
    short* owT    = (short*)w;                w += 8388608;      // 2048 x 2048 bf16
    short* Wt     = (short*)w;                w += 2097152;      // 512 x 2048 bf16
    short* Kr     = (short*)w;                w += 2097152;      // 2*4*2048*64 bf16
    short* Vb     = (short*)w;                w += 2097152;

    rope_table_k<<<dim3(256), dim3(256), 0, stream>>>(tab);
    f2b_k<<<dim3(1024), dim3(256), 0, stream>>>(kv_a, kva_bf);     // 2048x512

    transpose_f2b<<<dim3(16, 16), dim3(32, 8), 0, stream>>>(kv_b, kvbT, 512, 512);
    transpose_f2b<<<dim3(64, 64), dim3(32, 8), 0, stream>>>(o_w, owT, 2048, 2048);

    // Wt = (kv_a @ kv_b)^T = kvbT @ kvaT, via mgemm(A=kvbT, Bt=kva_bf)
    mgemm<64,64,64,true,false><<<dim3(32, 8), dim3(256), 0, stream>>>(kvbT, kva_bf, Wt, 512, 2048, 512);

    // Fused: KV = hs(f32) @ W, K=2048, RoPE + Kr/Vb epilogue (XCD-swizzled)
    kv_gemm<<<dim3(8, 64), dim3(256), 0, stream>>>(hs, Wt, tab, Kr, Vb);

    // dual-head GQA attention, KVBLK=64: grid (16 chunk-pairs, 16 head-pairs, B)
    attn_mfma<<<dim3(16, 16, 2), dim3(512), 0, stream>>>(hs, tab, Kr, Vb, AO);

    // out-proj: 128x128 tile, BK=64, XCD-swizzled -> grid (16, 32)
    mgemm<128,128,64,false,true><<<dim3(16, 32), dim3(256), 0, stream>>>(AO, owT, out, 4096, 2048, 2048);
}